// Round 8
// baseline (1167.674 us; speedup 1.0000x reference)
//
#include <hip/hip_runtime.h>
#include <cstddef>

// Problem constants: B=64, C=256, H*W=1024, N=B*HW=65536, n_embed=1024.
static constexpr int OUT_DIFF = 16777216;
static constexpr int OUT_IDX  = 33554432;
static constexpr int OUT_ENEW = 33619968;
static constexpr int OUT_CSN  = 33882112;
static constexpr int OUT_EAVG = 33883136;

// ---------------------------------------------------------------- K1: prep
// blocks 0..63 : embedT[k][c] = embed[c][k] via 64x64 LDS tile
// blocks 64..67: esq[k] (sequential ascending-c square-then-add, bitwise)
// block 68     : zero histogram counters
__global__ __launch_bounds__(256) void k_prep(const float* __restrict__ embed,
                                              float* __restrict__ embedT,
                                              float* __restrict__ esq,
                                              int* __restrict__ cnt) {
  const int wg = blockIdx.x;
  const int tid = threadIdx.x;
  if (wg < 64) {
    __shared__ float tt[64 * 65];
    const int k0 = (wg >> 2) * 64, c0 = (wg & 3) * 64;
#pragma unroll
    for (int r = 0; r < 4; ++r) {
      int i = tid + r * 256;
      int cc = i >> 4, kL = (i & 15) * 4;
      float4 v = *(const float4*)(embed + (size_t)(c0 + cc) * 1024 + k0 + kL);
      tt[(kL + 0) * 65 + cc] = v.x;
      tt[(kL + 1) * 65 + cc] = v.y;
      tt[(kL + 2) * 65 + cc] = v.z;
      tt[(kL + 3) * 65 + cc] = v.w;
    }
    __syncthreads();
#pragma unroll
    for (int r = 0; r < 4; ++r) {
      int i = tid + r * 256;
      int kk = i >> 4, cL = (i & 15) * 4;
      float4 o;
      o.x = tt[kk * 65 + cL + 0];
      o.y = tt[kk * 65 + cL + 1];
      o.z = tt[kk * 65 + cL + 2];
      o.w = tt[kk * 65 + cL + 3];
      *(float4*)(embedT + (size_t)(k0 + kk) * 256 + c0 + cL) = o;
    }
  } else if (wg < 68) {
    const int k = (wg - 64) * 256 + tid;
    {
#pragma clang fp contract(off)
      float s = 0.f;
#pragma unroll 1
      for (int c = 0; c < 256; ++c) { float u = embed[(size_t)c * 1024 + k]; s += u * u; }
      esq[k] = s;
    }
  } else {
    ((int4*)cnt)[tid] = make_int4(0, 0, 0, 0);
  }
}

// -------------------------------------------------------------- K2: argmin
// 2048 WGs x 256 thr (4 waves). Wave = 8 points x ALL 1024 codes.
// Lane l holds codes k = g*256 + l*4 + q (g=0..3, q=0..3): er loads are fully
// coalesced 1KB/instr; the 8-float x fragment is wave-uniform (1 cache line,
// broadcast). NO LDS staging, NO barriers in the main loop: fragments come
// straight from L1/L2. FMA chain per (point,code) is the same ascending-c
// single-accumulator fmaf chain as the passing version -> bit-identical dist.
__global__ __launch_bounds__(256) void k_argmin(const float* __restrict__ inp,
                                                const float* __restrict__ embed,
                                                const float* __restrict__ esq,
                                                int* __restrict__ idx_out,
                                                float* __restrict__ idxf_out,
                                                int* __restrict__ cnt) {
  __shared__ float xsqh[64];
  __shared__ float xsq_s[32];

  const int tid = threadIdx.x;
  const int lane = tid & 63;
  const int w = tid >> 6;
  const int n0 = blockIdx.x * 32;
  const int b = n0 >> 10;
  const int hwb = n0 & 1023;
  const float* xbase = inp + (size_t)b * 262144 + hwb;  // x[p][c] = xbase[c*1024+p]

  // xsq: numpy pairwise over 256 = pw(128)+pw(128); 64 threads, 2 per point
  if (tid < 64) {
#pragma clang fp contract(off)
    const int p = tid & 31, h = tid >> 5;
    const float* xb = xbase + (size_t)(h * 128) * 1024 + p;
    float r[8];
#pragma unroll
    for (int j = 0; j < 8; ++j) { float v = xb[(size_t)j * 1024]; r[j] = v * v; }
#pragma unroll 1
    for (int blk = 1; blk < 16; ++blk) {
#pragma unroll
      for (int j = 0; j < 8; ++j) { float v = xb[(size_t)(blk * 8 + j) * 1024]; r[j] += v * v; }
    }
    xsqh[h * 32 + p] = ((r[0] + r[1]) + (r[2] + r[3])) + ((r[4] + r[5]) + (r[6] + r[7]));
  }
  __syncthreads();
  if (tid < 32) xsq_s[tid] = xsqh[tid] + xsqh[32 + tid];
  __syncthreads();

  const float* xptr = xbase + w * 8;          // 8 contiguous points of this wave
  const float* eptr = embed + lane * 4;       // lane's code columns

  float acc[8][16];
#pragma unroll
  for (int p = 0; p < 8; ++p)
#pragma unroll
    for (int j = 0; j < 16; ++j) acc[p][j] = 0.f;

#pragma unroll 1
  for (int c = 0; c < 256; ++c) {
    const float* xc = xptr + (size_t)c * 1024;
    const float* ec = eptr + (size_t)c * 1024;
    float4 x0 = *(const float4*)(xc);
    float4 x1 = *(const float4*)(xc + 4);
    float4 e0 = *(const float4*)(ec);
    float4 e1 = *(const float4*)(ec + 256);
    float4 e2 = *(const float4*)(ec + 512);
    float4 e3 = *(const float4*)(ec + 768);
    float xr[8] = {x0.x, x0.y, x0.z, x0.w, x1.x, x1.y, x1.z, x1.w};
    float er[16] = {e0.x, e0.y, e0.z, e0.w, e1.x, e1.y, e1.z, e1.w,
                    e2.x, e2.y, e2.z, e2.w, e3.x, e3.y, e3.z, e3.w};
#pragma unroll
    for (int p = 0; p < 8; ++p)
#pragma unroll
      for (int j = 0; j < 16; ++j)
        acc[p][j] = __builtin_fmaf(xr[p], er[j], acc[p][j]);
  }

  // epilogue: dist = (xsq - 2*dot) + esq, reference rounding order;
  // per-thread scan is ascending-k; cross-lane reduce is lexicographic.
  float esqr[16];
#pragma unroll
  for (int g = 0; g < 4; ++g)
    *(float4*)&esqr[g * 4] = *(const float4*)(esq + g * 256 + lane * 4);
  float xq[8];
#pragma unroll
  for (int p = 0; p < 8; ++p) xq[p] = xsq_s[w * 8 + p];

#pragma unroll 1
  for (int p = 0; p < 8; ++p) {
    float v = 3.0e38f;
    int ii = 0;
#pragma unroll
    for (int g = 0; g < 4; ++g)
#pragma unroll
      for (int q = 0; q < 4; ++q) {
        int j = g * 4 + q;
        float d = (xq[p] - 2.0f * acc[p][j]) + esqr[j];
        int k = g * 256 + lane * 4 + q;
        if (d < v) { v = d; ii = k; }
      }
#pragma unroll
    for (int off = 1; off < 64; off <<= 1) {
      float ov = __shfl_xor(v, off);
      int oi = __shfl_xor(ii, off);
      if (ov < v || (ov == v && oi < ii)) { v = ov; ii = oi; }
    }
    if (lane == 0) {
      int n = n0 + w * 8 + p;
      idx_out[n] = ii;
      idxf_out[n] = (float)ii;
      atomicAdd(cnt + ii, 1);
    }
  }
}

// ---------------------------------------------------------------- K3: scan
__global__ __launch_bounds__(1024) void k_scan(const int* __restrict__ cnt,
                                               const float* __restrict__ cs_in,
                                               int* __restrict__ offs,
                                               int* __restrict__ cursor,
                                               float* __restrict__ csn_out,
                                               float* __restrict__ nval) {
  __shared__ int sc[1024];
  __shared__ float red[1024];
  const int tid = threadIdx.x;
  const int c = cnt[tid];
  const float csv = cs_in[tid];
  sc[tid] = c;
  red[tid] = csv;
  __syncthreads();
#pragma unroll 1
  for (int off = 1; off < 1024; off <<= 1) {
    int v = sc[tid];
    int add = (tid >= off) ? sc[tid - off] : 0;
    __syncthreads();
    sc[tid] = v + add;
    __syncthreads();
  }
  const int incl = sc[tid];
  const int start = incl - c;
  offs[tid] = start;
  cursor[tid] = start;
  if (tid == 1023) offs[1024] = incl;
  csn_out[tid] = csv * 0.99f + (float)c * 0.01f;
#pragma unroll 1
  for (int off = 512; off > 0; off >>= 1) {
    if (tid < off) red[tid] += red[tid + off];
    __syncthreads();
  }
  if (tid == 0) nval[0] = 0.99f * red[0] + 0.01f * 65536.0f;
}

// ------------------------------------------------------------- K4: scatter
__global__ __launch_bounds__(256) void k_scatter(const int* __restrict__ idx,
                                                 int* __restrict__ cursor,
                                                 int* __restrict__ bucket) {
  const int n = blockIdx.x * 256 + threadIdx.x;
  const int k = idx[n];
  const int pos = atomicAdd(cursor + k, 1);
  bucket[pos] = n;
}

// --------------------------------------------------------------- K5: diffq
// Reads inp directly (no flat intermediate): LDS-transpose tile, compute
// diff = q - x (write N,C), qst = x + diff, transpose-write q_out (B,C,HW).
__global__ __launch_bounds__(256) void k_diffq(const int* __restrict__ idx,
                                               const float* __restrict__ embedT,
                                               const float* __restrict__ inp,
                                               float* __restrict__ diff,
                                               float* __restrict__ q_out) {
  const int tid = threadIdx.x;
  const int b = blockIdx.x >> 4;
  const int hw0 = (blockIdx.x & 15) * 64;
  const int n0 = b * 1024 + hw0;
  __shared__ float t[64 * 257];
#pragma unroll
  for (int r = 0; r < 16; ++r) {
    int i = tid + r * 256;
    int c = i >> 4, l = i & 15;
    float4 v = *(const float4*)(inp + (size_t)b * 262144 + (size_t)c * 1024 + hw0 + l * 4);
    t[(l * 4 + 0) * 257 + c] = v.x;
    t[(l * 4 + 1) * 257 + c] = v.y;
    t[(l * 4 + 2) * 257 + c] = v.z;
    t[(l * 4 + 3) * 257 + c] = v.w;
  }
  __syncthreads();
#pragma unroll
  for (int r = 0; r < 16; ++r) {
    int i = tid + r * 256;
    int hw = i >> 6, c4 = (i & 63) * 4;
    int n = n0 + hw;
    int kk = idx[n];
    float4 q = *(const float4*)(embedT + (size_t)kk * 256 + c4);
    float x0 = t[hw * 257 + c4 + 0];
    float x1 = t[hw * 257 + c4 + 1];
    float x2 = t[hw * 257 + c4 + 2];
    float x3 = t[hw * 257 + c4 + 3];
    float4 d;
    d.x = q.x - x0; d.y = q.y - x1; d.z = q.z - x2; d.w = q.w - x3;
    *(float4*)(diff + (size_t)n * 256 + c4) = d;
    t[hw * 257 + c4 + 0] = x0 + d.x;
    t[hw * 257 + c4 + 1] = x1 + d.y;
    t[hw * 257 + c4 + 2] = x2 + d.z;
    t[hw * 257 + c4 + 3] = x3 + d.w;
  }
  __syncthreads();
#pragma unroll
  for (int r = 0; r < 16; ++r) {
    int i = tid + r * 256;
    int c = i >> 4, l = i & 15;
    float4 o;
    o.x = t[(l * 4 + 0) * 257 + c];
    o.y = t[(l * 4 + 1) * 257 + c];
    o.z = t[(l * 4 + 2) * 257 + c];
    o.w = t[(l * 4 + 3) * 257 + c];
    *(float4*)(q_out + (size_t)b * 262144 + (size_t)c * 1024 + hw0 + l * 4) = o;
  }
}

// -------------------------------------------------------------- K6: update
// One WG per code k. sum_x[k][c] = cnt_k * embedT[k][c] - sum(diff rows):
// all points in bucket k share q = embedT[k], and diff = q - x.
__global__ __launch_bounds__(256) void k_update(const int* __restrict__ offs,
                                                const int* __restrict__ bucket,
                                                const float* __restrict__ diff,
                                                const float* __restrict__ embedT,
                                                float* __restrict__ sums) {
  const int k = blockIdx.x;
  const int tid = threadIdx.x;
  const int w = tid >> 6, lane = tid & 63;
  __shared__ float sums_s[4][256];
  const int start = offs[k], end = offs[k + 1];
  float4 acc = make_float4(0.f, 0.f, 0.f, 0.f);
#pragma unroll 1
  for (int e = start + w; e < end; e += 4) {
    const float* row = diff + (size_t)bucket[e] * 256;
    float4 d4 = *(const float4*)(row + lane * 4);
    acc.x += d4.x; acc.y += d4.y; acc.z += d4.z; acc.w += d4.w;
  }
  *(float4*)&sums_s[w][lane * 4] = acc;
  __syncthreads();
  const float dsum = ((sums_s[0][tid] + sums_s[1][tid]) + sums_s[2][tid]) + sums_s[3][tid];
  const float cntf = (float)(end - start);
  sums[(size_t)k * 256 + tid] = cntf * embedT[(size_t)k * 256 + tid] - dsum;
}

// ----------------------------------------------------------------- K7: ema
__global__ __launch_bounds__(256) void k_ema(const float* __restrict__ sums,
                                             const float* __restrict__ eavg,
                                             const float* __restrict__ csn,
                                             const float* __restrict__ nval,
                                             float* __restrict__ eavgn,
                                             float* __restrict__ enew) {
  __shared__ float t[64 * 65];
  __shared__ float csks[64];
  const int tid = threadIdx.x;
  const int k0 = (blockIdx.x >> 2) * 64, c0 = (blockIdx.x & 3) * 64;
  if (tid < 64) {
    float nv = nval[0];
    float cv = csn[k0 + tid];
    csks[tid] = (cv + 1e-5f) / (nv + 0.01024f) * nv;
  }
#pragma unroll
  for (int r = 0; r < 4; ++r) {
    int i = tid + r * 256;
    int kk = i >> 4, cL = (i & 15) * 4;
    float4 v = *(const float4*)(sums + (size_t)(k0 + kk) * 256 + c0 + cL);
    t[(cL + 0) * 65 + kk] = v.x;
    t[(cL + 1) * 65 + kk] = v.y;
    t[(cL + 2) * 65 + kk] = v.z;
    t[(cL + 3) * 65 + kk] = v.w;
  }
  __syncthreads();
#pragma unroll
  for (int r = 0; r < 4; ++r) {
    int i = tid + r * 256;
    int c = i >> 4, kL = (i & 15) * 4;
    size_t o = (size_t)(c0 + c) * 1024 + k0 + kL;
    float4 ev = *(const float4*)(eavg + o);
    float4 ean, en;
    ean.x = ev.x * 0.99f + t[c * 65 + kL + 0] * 0.01f;
    ean.y = ev.y * 0.99f + t[c * 65 + kL + 1] * 0.01f;
    ean.z = ev.z * 0.99f + t[c * 65 + kL + 2] * 0.01f;
    ean.w = ev.w * 0.99f + t[c * 65 + kL + 3] * 0.01f;
    en.x = ean.x / csks[kL + 0];
    en.y = ean.y / csks[kL + 1];
    en.z = ean.z / csks[kL + 2];
    en.w = ean.w / csks[kL + 3];
    *(float4*)(eavgn + o) = ean;
    *(float4*)(enew + o) = en;
  }
}

// ----------------------------------------------------------------- launch
extern "C" void kernel_launch(void* const* d_in, const int* in_sizes, int n_in,
                              void* d_out, int out_size, void* d_ws, size_t ws_size,
                              hipStream_t stream) {
  (void)in_sizes; (void)n_in; (void)out_size; (void)ws_size;
  const float* inp   = (const float*)d_in[0];
  const float* embed = (const float*)d_in[1];
  const float* cs_in = (const float*)d_in[2];
  const float* eavg  = (const float*)d_in[3];
  float* out = (float*)d_out;

  // workspace layout (float units)
  int*   idx_ws = (int*)d_ws;                    // 65536 ints
  int*   bucket = idx_ws + 65536;                // 65536 ints
  int*   cnt    = bucket + 65536;                // 1024 ints (zeroed by k_prep)
  int*   offs   = cnt + 1024;                    // 1025 ints
  int*   cursor = offs + 1536;                   // 1024 ints
  float* wsf    = (float*)d_ws;
  float* nval   = wsf + 136192;                  // 1
  float* esq    = wsf + 136448;                  // 1024
  float* sums   = wsf + 137472;                  // 262144
  float* embedT = wsf + 399616;                  // 262144

  hipLaunchKernelGGL(k_prep,    dim3(69),   dim3(256),  0, stream, embed, embedT, esq, cnt);
  hipLaunchKernelGGL(k_argmin,  dim3(2048), dim3(256),  0, stream, inp, embed, esq,
                     idx_ws, out + OUT_IDX, cnt);
  hipLaunchKernelGGL(k_scan,    dim3(1),    dim3(1024), 0, stream, cnt, cs_in, offs, cursor,
                     out + OUT_CSN, nval);
  hipLaunchKernelGGL(k_scatter, dim3(256),  dim3(256),  0, stream, idx_ws, cursor, bucket);
  hipLaunchKernelGGL(k_diffq,   dim3(1024), dim3(256),  0, stream, idx_ws, embedT, inp,
                     out + OUT_DIFF, out);
  hipLaunchKernelGGL(k_update,  dim3(1024), dim3(256),  0, stream, offs, bucket,
                     out + OUT_DIFF, embedT, sums);
  hipLaunchKernelGGL(k_ema,     dim3(64),   dim3(256),  0, stream, sums, eavg, out + OUT_CSN,
                     nval, out + OUT_EAVG, out + OUT_ENEW);
}

// Round 9
// 917.644 us; speedup vs baseline: 1.2725x; 1.2725x over previous
//
#include <hip/hip_runtime.h>
#include <cstddef>

// Problem constants: B=64, C=256, H*W=1024, N=B*HW=65536, n_embed=1024.
static constexpr int OUT_DIFF = 16777216;
static constexpr int OUT_IDX  = 33554432;
static constexpr int OUT_ENEW = 33619968;
static constexpr int OUT_CSN  = 33882112;
static constexpr int OUT_EAVG = 33883136;

// ---------------------------------------------------------------- K1: prep
__global__ __launch_bounds__(256) void k_prep(const float* __restrict__ embed,
                                              float* __restrict__ embedT,
                                              float* __restrict__ esq,
                                              int* __restrict__ cnt) {
  const int wg = blockIdx.x;
  const int tid = threadIdx.x;
  if (wg < 64) {
    __shared__ float tt[64 * 65];
    const int k0 = (wg >> 2) * 64, c0 = (wg & 3) * 64;
#pragma unroll
    for (int r = 0; r < 4; ++r) {
      int i = tid + r * 256;
      int cc = i >> 4, kL = (i & 15) * 4;
      float4 v = *(const float4*)(embed + (size_t)(c0 + cc) * 1024 + k0 + kL);
      tt[(kL + 0) * 65 + cc] = v.x;
      tt[(kL + 1) * 65 + cc] = v.y;
      tt[(kL + 2) * 65 + cc] = v.z;
      tt[(kL + 3) * 65 + cc] = v.w;
    }
    __syncthreads();
#pragma unroll
    for (int r = 0; r < 4; ++r) {
      int i = tid + r * 256;
      int kk = i >> 4, cL = (i & 15) * 4;
      float4 o;
      o.x = tt[kk * 65 + cL + 0];
      o.y = tt[kk * 65 + cL + 1];
      o.z = tt[kk * 65 + cL + 2];
      o.w = tt[kk * 65 + cL + 3];
      *(float4*)(embedT + (size_t)(k0 + kk) * 256 + c0 + cL) = o;
    }
  } else if (wg < 68) {
    const int k = (wg - 64) * 256 + tid;
    {
#pragma clang fp contract(off)
      float s = 0.f;
#pragma unroll 1
      for (int c = 0; c < 256; ++c) { float u = embed[(size_t)c * 1024 + k]; s += u * u; }
      esq[k] = s;
    }
  } else {
    ((int4*)cnt)[tid] = make_int4(0, 0, 0, 0);
  }
}

// -------------------------------------------------------------- K2: argmin
// 2048 WGs x 256 thr (4 waves), block = 32 points. Wave w owns code quarter
// k in [256w, 256w+256): per c-step it loads ONE coalesced 1KB e-fragment
// (lane l -> codes 256w + l*4 + q) and 32 wave-uniform x floats. Block reads
// embed exactly once (1MB, L2-resident). acc[32][4] fully unrolled in VGPRs;
// __launch_bounds__(256,2) gives the 256-VGPR budget (R8's 84-reg spill fix).
// Per-(point,code) chain: ascending-c single-accumulator fmaf -> bit-identical
// dist; quarters combined in ascending-k order with strict < -> np first-min.
__global__ __launch_bounds__(256, 2) void k_argmin(const float* __restrict__ inp,
                                                   const float* __restrict__ embed,
                                                   const float* __restrict__ esq,
                                                   int* __restrict__ idx_out,
                                                   float* __restrict__ idxf_out,
                                                   int* __restrict__ cnt) {
  __shared__ float xsqh[64];
  __shared__ float xsq_s[32];
  __shared__ float bv_s[4][32];
  __shared__ int   bi_s[4][32];

  const int tid = threadIdx.x;
  const int lane = tid & 63;
  const int w = tid >> 6;
  const int n0 = blockIdx.x * 32;
  const int b = n0 >> 10;
  const int hwb = n0 & 1023;
  const float* xbase = inp + (size_t)b * 262144 + hwb;  // x[p][c] = xbase[c*1024+p]

  // xsq: numpy pairwise over 256 = pw(128)+pw(128); 64 threads, 2 per point
  if (tid < 64) {
#pragma clang fp contract(off)
    const int p = tid & 31, h = tid >> 5;
    const float* xb = xbase + (size_t)(h * 128) * 1024 + p;
    float r[8];
#pragma unroll
    for (int j = 0; j < 8; ++j) { float v = xb[(size_t)j * 1024]; r[j] = v * v; }
#pragma unroll 1
    for (int blk = 1; blk < 16; ++blk) {
#pragma unroll
      for (int j = 0; j < 8; ++j) { float v = xb[(size_t)(blk * 8 + j) * 1024]; r[j] += v * v; }
    }
    xsqh[h * 32 + p] = ((r[0] + r[1]) + (r[2] + r[3])) + ((r[4] + r[5]) + (r[6] + r[7]));
  }
  __syncthreads();
  if (tid < 32) xsq_s[tid] = xsqh[tid] + xsqh[32 + tid];
  __syncthreads();

  const float* eptr = embed + (w << 8) + (lane << 2);  // this lane's 4 codes

  float acc[32][4];
#pragma unroll
  for (int p = 0; p < 32; ++p)
#pragma unroll
    for (int q = 0; q < 4; ++q) acc[p][q] = 0.f;

#pragma unroll 1
  for (int c = 0; c < 256; ++c) {
    const float* xc = xbase + (size_t)c * 1024;
    float4 ev = *(const float4*)(eptr + (size_t)c * 1024);
    float xv[32];
#pragma unroll
    for (int t = 0; t < 8; ++t)
      *(float4*)&xv[t * 4] = *(const float4*)(xc + t * 4);
    float er[4] = {ev.x, ev.y, ev.z, ev.w};
#pragma unroll
    for (int p = 0; p < 32; ++p)
#pragma unroll
      for (int q = 0; q < 4; ++q)
        acc[p][q] = __builtin_fmaf(xv[p], er[q], acc[p][q]);
  }

  // epilogue: dist = (xsq - 2*dot) + esq, reference rounding order.
  float esqr[4];
  *(float4*)esqr = *(const float4*)(esq + (w << 8) + (lane << 2));

#pragma unroll
  for (int p = 0; p < 32; ++p) {
    float xq = xsq_s[p];
    float v = 3.0e38f;
    int ii = 0;
#pragma unroll
    for (int q = 0; q < 4; ++q) {
      float d = (xq - 2.0f * acc[p][q]) + esqr[q];
      int k = (w << 8) + (lane << 2) + q;
      if (d < v) { v = d; ii = k; }
    }
#pragma unroll
    for (int off = 1; off < 64; off <<= 1) {
      float ov = __shfl_xor(v, off);
      int oi = __shfl_xor(ii, off);
      if (ov < v || (ov == v && oi < ii)) { v = ov; ii = oi; }
    }
    if (lane == 0) { bv_s[w][p] = v; bi_s[w][p] = ii; }
  }
  __syncthreads();
  if (tid < 32) {
    const int p = tid;
    float v = bv_s[0][p];
    int ii = bi_s[0][p];
#pragma unroll
    for (int qd = 1; qd < 4; ++qd) {
      float ov = bv_s[qd][p];
      int oi = bi_s[qd][p];
      if (ov < v || (ov == v && oi < ii)) { v = ov; ii = oi; }
    }
    int n = n0 + p;
    idx_out[n] = ii;
    idxf_out[n] = (float)ii;
    atomicAdd(cnt + ii, 1);
  }
}

// ---------------------------------------------------------------- K3: scan
__global__ __launch_bounds__(1024) void k_scan(const int* __restrict__ cnt,
                                               const float* __restrict__ cs_in,
                                               int* __restrict__ offs,
                                               int* __restrict__ cursor,
                                               float* __restrict__ csn_out,
                                               float* __restrict__ nval) {
  __shared__ int sc[1024];
  __shared__ float red[1024];
  const int tid = threadIdx.x;
  const int c = cnt[tid];
  const float csv = cs_in[tid];
  sc[tid] = c;
  red[tid] = csv;
  __syncthreads();
#pragma unroll 1
  for (int off = 1; off < 1024; off <<= 1) {
    int v = sc[tid];
    int add = (tid >= off) ? sc[tid - off] : 0;
    __syncthreads();
    sc[tid] = v + add;
    __syncthreads();
  }
  const int incl = sc[tid];
  const int start = incl - c;
  offs[tid] = start;
  cursor[tid] = start;
  if (tid == 1023) offs[1024] = incl;
  csn_out[tid] = csv * 0.99f + (float)c * 0.01f;
#pragma unroll 1
  for (int off = 512; off > 0; off >>= 1) {
    if (tid < off) red[tid] += red[tid + off];
    __syncthreads();
  }
  if (tid == 0) nval[0] = 0.99f * red[0] + 0.01f * 65536.0f;
}

// ------------------------------------------------------------- K4: scatter
__global__ __launch_bounds__(256) void k_scatter(const int* __restrict__ idx,
                                                 int* __restrict__ cursor,
                                                 int* __restrict__ bucket) {
  const int n = blockIdx.x * 256 + threadIdx.x;
  const int k = idx[n];
  const int pos = atomicAdd(cursor + k, 1);
  bucket[pos] = n;
}

// --------------------------------------------------------------- K5: diffq
__global__ __launch_bounds__(256) void k_diffq(const int* __restrict__ idx,
                                               const float* __restrict__ embedT,
                                               const float* __restrict__ inp,
                                               float* __restrict__ diff,
                                               float* __restrict__ q_out) {
  const int tid = threadIdx.x;
  const int b = blockIdx.x >> 4;
  const int hw0 = (blockIdx.x & 15) * 64;
  const int n0 = b * 1024 + hw0;
  __shared__ float t[64 * 257];
#pragma unroll
  for (int r = 0; r < 16; ++r) {
    int i = tid + r * 256;
    int c = i >> 4, l = i & 15;
    float4 v = *(const float4*)(inp + (size_t)b * 262144 + (size_t)c * 1024 + hw0 + l * 4);
    t[(l * 4 + 0) * 257 + c] = v.x;
    t[(l * 4 + 1) * 257 + c] = v.y;
    t[(l * 4 + 2) * 257 + c] = v.z;
    t[(l * 4 + 3) * 257 + c] = v.w;
  }
  __syncthreads();
#pragma unroll
  for (int r = 0; r < 16; ++r) {
    int i = tid + r * 256;
    int hw = i >> 6, c4 = (i & 63) * 4;
    int n = n0 + hw;
    int kk = idx[n];
    float4 q = *(const float4*)(embedT + (size_t)kk * 256 + c4);
    float x0 = t[hw * 257 + c4 + 0];
    float x1 = t[hw * 257 + c4 + 1];
    float x2 = t[hw * 257 + c4 + 2];
    float x3 = t[hw * 257 + c4 + 3];
    float4 d;
    d.x = q.x - x0; d.y = q.y - x1; d.z = q.z - x2; d.w = q.w - x3;
    *(float4*)(diff + (size_t)n * 256 + c4) = d;
    t[hw * 257 + c4 + 0] = x0 + d.x;
    t[hw * 257 + c4 + 1] = x1 + d.y;
    t[hw * 257 + c4 + 2] = x2 + d.z;
    t[hw * 257 + c4 + 3] = x3 + d.w;
  }
  __syncthreads();
#pragma unroll
  for (int r = 0; r < 16; ++r) {
    int i = tid + r * 256;
    int c = i >> 4, l = i & 15;
    float4 o;
    o.x = t[(l * 4 + 0) * 257 + c];
    o.y = t[(l * 4 + 1) * 257 + c];
    o.z = t[(l * 4 + 2) * 257 + c];
    o.w = t[(l * 4 + 3) * 257 + c];
    *(float4*)(q_out + (size_t)b * 262144 + (size_t)c * 1024 + hw0 + l * 4) = o;
  }
}

// -------------------------------------------------------------- K6: update
__global__ __launch_bounds__(256) void k_update(const int* __restrict__ offs,
                                                const int* __restrict__ bucket,
                                                const float* __restrict__ diff,
                                                const float* __restrict__ embedT,
                                                float* __restrict__ sums) {
  const int k = blockIdx.x;
  const int tid = threadIdx.x;
  const int w = tid >> 6, lane = tid & 63;
  __shared__ float sums_s[4][256];
  const int start = offs[k], end = offs[k + 1];
  float4 acc = make_float4(0.f, 0.f, 0.f, 0.f);
#pragma unroll 1
  for (int e = start + w; e < end; e += 4) {
    const float* row = diff + (size_t)bucket[e] * 256;
    float4 d4 = *(const float4*)(row + lane * 4);
    acc.x += d4.x; acc.y += d4.y; acc.z += d4.z; acc.w += d4.w;
  }
  *(float4*)&sums_s[w][lane * 4] = acc;
  __syncthreads();
  const float dsum = ((sums_s[0][tid] + sums_s[1][tid]) + sums_s[2][tid]) + sums_s[3][tid];
  const float cntf = (float)(end - start);
  sums[(size_t)k * 256 + tid] = cntf * embedT[(size_t)k * 256 + tid] - dsum;
}

// ----------------------------------------------------------------- K7: ema
__global__ __launch_bounds__(256) void k_ema(const float* __restrict__ sums,
                                             const float* __restrict__ eavg,
                                             const float* __restrict__ csn,
                                             const float* __restrict__ nval,
                                             float* __restrict__ eavgn,
                                             float* __restrict__ enew) {
  __shared__ float t[64 * 65];
  __shared__ float csks[64];
  const int tid = threadIdx.x;
  const int k0 = (blockIdx.x >> 2) * 64, c0 = (blockIdx.x & 3) * 64;
  if (tid < 64) {
    float nv = nval[0];
    float cv = csn[k0 + tid];
    csks[tid] = (cv + 1e-5f) / (nv + 0.01024f) * nv;
  }
#pragma unroll
  for (int r = 0; r < 4; ++r) {
    int i = tid + r * 256;
    int kk = i >> 4, cL = (i & 15) * 4;
    float4 v = *(const float4*)(sums + (size_t)(k0 + kk) * 256 + c0 + cL);
    t[(cL + 0) * 65 + kk] = v.x;
    t[(cL + 1) * 65 + kk] = v.y;
    t[(cL + 2) * 65 + kk] = v.z;
    t[(cL + 3) * 65 + kk] = v.w;
  }
  __syncthreads();
#pragma unroll
  for (int r = 0; r < 4; ++r) {
    int i = tid + r * 256;
    int c = i >> 4, kL = (i & 15) * 4;
    size_t o = (size_t)(c0 + c) * 1024 + k0 + kL;
    float4 ev = *(const float4*)(eavg + o);
    float4 ean, en;
    ean.x = ev.x * 0.99f + t[c * 65 + kL + 0] * 0.01f;
    ean.y = ev.y * 0.99f + t[c * 65 + kL + 1] * 0.01f;
    ean.z = ev.z * 0.99f + t[c * 65 + kL + 2] * 0.01f;
    ean.w = ev.w * 0.99f + t[c * 65 + kL + 3] * 0.01f;
    en.x = ean.x / csks[kL + 0];
    en.y = ean.y / csks[kL + 1];
    en.z = ean.z / csks[kL + 2];
    en.w = ean.w / csks[kL + 3];
    *(float4*)(eavgn + o) = ean;
    *(float4*)(enew + o) = en;
  }
}

// ----------------------------------------------------------------- launch
extern "C" void kernel_launch(void* const* d_in, const int* in_sizes, int n_in,
                              void* d_out, int out_size, void* d_ws, size_t ws_size,
                              hipStream_t stream) {
  (void)in_sizes; (void)n_in; (void)out_size; (void)ws_size;
  const float* inp   = (const float*)d_in[0];
  const float* embed = (const float*)d_in[1];
  const float* cs_in = (const float*)d_in[2];
  const float* eavg  = (const float*)d_in[3];
  float* out = (float*)d_out;

  // workspace layout (float units)
  int*   idx_ws = (int*)d_ws;                    // 65536 ints
  int*   bucket = idx_ws + 65536;                // 65536 ints
  int*   cnt    = bucket + 65536;                // 1024 ints (zeroed by k_prep)
  int*   offs   = cnt + 1024;                    // 1025 ints
  int*   cursor = offs + 1536;                   // 1024 ints
  float* wsf    = (float*)d_ws;
  float* nval   = wsf + 136192;                  // 1
  float* esq    = wsf + 136448;                  // 1024
  float* sums   = wsf + 137472;                  // 262144
  float* embedT = wsf + 399616;                  // 262144

  hipLaunchKernelGGL(k_prep,    dim3(69),   dim3(256),  0, stream, embed, embedT, esq, cnt);
  hipLaunchKernelGGL(k_argmin,  dim3(2048), dim3(256),  0, stream, inp, embed, esq,
                     idx_ws, out + OUT_IDX, cnt);
  hipLaunchKernelGGL(k_scan,    dim3(1),    dim3(1024), 0, stream, cnt, cs_in, offs, cursor,
                     out + OUT_CSN, nval);
  hipLaunchKernelGGL(k_scatter, dim3(256),  dim3(256),  0, stream, idx_ws, cursor, bucket);
  hipLaunchKernelGGL(k_diffq,   dim3(1024), dim3(256),  0, stream, idx_ws, embedT, inp,
                     out + OUT_DIFF, out);
  hipLaunchKernelGGL(k_update,  dim3(1024), dim3(256),  0, stream, offs, bucket,
                     out + OUT_DIFF, embedT, sums);
  hipLaunchKernelGGL(k_ema,     dim3(64),   dim3(256),  0, stream, sums, eavg, out + OUT_CSN,
                     nval, out + OUT_EAVG, out + OUT_ENEW);
}